// Round 1
// baseline (284.435 us; speedup 1.0000x reference)
//
#include <hip/hip_runtime.h>
#include <hip/hip_bf16.h>

typedef __attribute__((ext_vector_type(8))) short short8;
typedef __attribute__((ext_vector_type(4))) float floatx4;

#define NN     4096
#define DIN    128
#define EDIM   192
#define DMODEL 128

__device__ __forceinline__ unsigned short f2bf(float f) {
    union { float f; unsigned int i; } x; x.f = f;
    unsigned int u = x.i;
    u += 0x7FFFu + ((u >> 16) & 1u);   // RNE
    return (unsigned short)(u >> 16);
}

__device__ __forceinline__ unsigned int pk2(float lo, float hi) {
    union { __hip_bfloat162 v; unsigned int u; } cv;
    cv.v = __float22bfloat162_rn(make_float2(lo, hi));
    return cv.u;
}

__device__ __forceinline__ short8 cvt8(const float4 a, const float4 b) {
    union { short8 s; unsigned int u[4]; } r;
    r.u[0] = pk2(a.x, a.y);
    r.u[1] = pk2(a.z, a.w);
    r.u[2] = pk2(b.x, b.y);
    r.u[3] = pk2(b.z, b.w);
    return r.s;
}

// Pack W (576x128 fp32, row-major, original k = 3c+j feat / 384+e edge) into
// bf16 MFMA B-fragment order under PERMUTED k-order kt = j*128+c (feat), kt=k (edge):
// wf[((gs*8+ct)*64+lane)*8+jj] = bf16(W[korig(kt)*128 + ct*16 + (lane&15)]),
// kt = gs*32 + (lane>>4)*8 + jj.
__global__ void prep_w(const float* __restrict__ W, unsigned short* __restrict__ wf) {
    const int t = blockIdx.x * 256 + threadIdx.x;      // 288*256 == 73728 exactly
    const int jj   = t & 7;
    const int lane = (t >> 3) & 63;
    const int ct   = (t >> 9) & 7;
    const int gs   = t >> 12;
    const int kt = gs * 32 + ((lane >> 4) << 3) + jj;
    const int korig = (kt < 384) ? ((kt & 127) * 3 + (kt >> 7)) : kt;
    const int n = ct * 16 + (lane & 15);
    wf[t] = f2bf(W[korig * DMODEL + n]);
}

// Fully fused main kernel (one launch does GEMM+epilogue, m3/o_m, and adj copy).
// Grid doubled vs previous version (512 -> 1024 blocks) to lift the occupancy
// cap (was 2 blocks/CU = 25% max; now 4 blocks/CU = 50% max). Each block:
// 4 waves, 64 rows of batch b (one 16-row MFMA tile per wave), 128 cols.
__global__ __launch_bounds__(256, 4) void main_k(
    const float* __restrict__ feat,
    const float* __restrict__ edgef,
    const unsigned short* __restrict__ wfrag,
    const float* __restrict__ bias,
    const float* __restrict__ mask,
    const floatx4* __restrict__ adj4,
    floatx4* __restrict__ o_adj4,
    float* __restrict__ o_res,
    float* __restrict__ o_out,
    float* __restrict__ o_m)
{
    __shared__ float m3s[64];

    const int tid  = threadIdx.x;
    const int lane = tid & 63;
    const int wv   = tid >> 6;
    const int nn   = lane & 15;
    const int quad = lane >> 4;

    const int blk = blockIdx.x;
    const int b   = blk >> 6;                 // batch 0..15
    const int i0  = (blk & 63) << 6;          // 64-row tile base
    const int p   = b & 3;

    // ---- m3 (3-window mask max) into LDS; blocks b<4 also emit output 3 ----
    if (tid < 64) {
        const int i = i0 + tid;
        float v = mask[p * NN + i];
        if (i + 1 < NN) v = fmaxf(v, mask[p * NN + i + 1]);
        if (i + 2 < NN) v = fmaxf(v, mask[p * NN + i + 2]);
        m3s[tid] = v;
        if (b < 4) o_m[p * NN + i] = v;
    }
    __syncthreads();

    const float* fb = feat  + (size_t)b * NN * DIN;
    const float* eb = edgef + (size_t)b * NN * EDIM;

    const int rowb = i0 + wv * 16 + nn;        // A-row for this lane

    floatx4 acc[8];
    #pragma unroll
    for (int ct = 0; ct < 8; ++ct)
        acc[ct] = (floatx4){0.f, 0.f, 0.f, 0.f};

    const short8* wf8 = (const short8*)wfrag;

    // ---- feature K region: kt = j*128 + sl*32 + quad*8 + jj ----
    #pragma unroll
    for (int j = 0; j < 3; ++j) {
        #pragma unroll
        for (int sl = 0; sl < 4; ++sl) {
            const int gs = j * 4 + sl;
            short8 bfr[8];
            #pragma unroll
            for (int ct = 0; ct < 8; ++ct)
                bfr[ct] = wf8[(gs * 8 + ct) * 64 + lane];
            const int row = rowb + j;
            float4 a0 = make_float4(0.f, 0.f, 0.f, 0.f);
            float4 a1 = a0;
            if (row < NN) {
                const float* s = fb + (size_t)row * DIN + sl * 32 + quad * 8;
                a0 = *(const float4*)s;
                a1 = *(const float4*)(s + 4);
            }
            const short8 afr = cvt8(a0, a1);
            #pragma unroll
            for (int ct = 0; ct < 8; ++ct)
                acc[ct] = __builtin_amdgcn_mfma_f32_16x16x32_bf16(
                    afr, bfr[ct], acc[ct], 0, 0, 0);
        }
    }

    // ---- edge K region: kt = 384 + eg*32 + quad*8 + jj ----
    #pragma unroll
    for (int eg = 0; eg < 6; ++eg) {
        const int gs = 12 + eg;
        short8 bfr[8];
        #pragma unroll
        for (int ct = 0; ct < 8; ++ct)
            bfr[ct] = wf8[(gs * 8 + ct) * 64 + lane];
        const float* s = eb + (size_t)rowb * EDIM + eg * 32 + quad * 8;   // rowb < NN always
        const float4 a0 = *(const float4*)s;
        const float4 a1 = *(const float4*)(s + 4);
        const short8 afr = cvt8(a0, a1);
        #pragma unroll
        for (int ct = 0; ct < 8; ++ct)
            acc[ct] = __builtin_amdgcn_mfma_f32_16x16x32_bf16(
                afr, bfr[ct], acc[ct], 0, 0, 0);
    }

    // ---- epilogue: bias + ReLU, jump (3-row feature mean), mask, fp32 stores ----
    float biasv[8];
    #pragma unroll
    for (int ct = 0; ct < 8; ++ct)
        biasv[ct] = bias[ct * 16 + nn];

    const float inv3 = 1.0f / 3.0f;
    const int rbase = wv * 16 + quad * 4;     // C/D: row = quad*4 + reg
    float mv[4];
    #pragma unroll
    for (int reg = 0; reg < 4; ++reg)
        mv[reg] = m3s[rbase + reg];

    #pragma unroll
    for (int ct = 0; ct < 8; ++ct) {
        const int col = ct * 16 + nn;         // C/D: col = lane&15
        float fv[6];
        #pragma unroll
        for (int t6 = 0; t6 < 6; ++t6) {
            const int row = i0 + rbase + t6;
            fv[t6] = (row < NN) ? fb[(size_t)row * DIN + col] : 0.f;
        }
        #pragma unroll
        for (int reg = 0; reg < 4; ++reg) {
            float o = acc[ct][reg] + biasv[ct];
            o = fmaxf(o, 0.f);
            const float jmp = (fv[reg] + fv[reg + 1] + fv[reg + 2]) * inv3;
            const size_t off = ((size_t)b * NN + (i0 + rbase + reg)) * DMODEL + col;
            const float mm = mv[reg];
            __builtin_nontemporal_store(mm * o, &o_out[off]);
            __builtin_nontemporal_store(mm * (o + jmp), &o_res[off]);
        }
    }

    // ---- adj passthrough slice: 1024 blocks x 256 thr x 16 float4 = 4096*4096 ----
    {
        const int idx = blk * 256 + tid;                  // 262144 threads
        #pragma unroll
        for (int i = 0; i < 16; ++i) {
            const floatx4 v = __builtin_nontemporal_load(&adj4[idx + i * 262144]);
            __builtin_nontemporal_store(v, &o_adj4[idx + i * 262144]);
        }
    }
}

extern "C" void kernel_launch(void* const* d_in, const int* in_sizes, int n_in,
                              void* d_out, int out_size, void* d_ws, size_t ws_size,
                              hipStream_t stream) {
    const float* adj   = (const float*)d_in[0];
    const float* feat  = (const float*)d_in[1];
    const float* edgef = (const float*)d_in[2];
    const float* mask  = (const float*)d_in[3];
    const float* W     = (const float*)d_in[4];
    const float* bias  = (const float*)d_in[5];

    float* out   = (float*)d_out;
    float* o_adj = out;
    float* o_res = out + (size_t)16777216;              // 4096*4096
    float* o_out = o_res + (size_t)8388608;             // 16*4096*128
    float* o_m   = o_out + (size_t)8388608;             // + 16*4096*128 -> 4*4096 tail

    unsigned short* wfrag = (unsigned short*)d_ws;      // 73728 * 2 B

    prep_w<<<288, 256, 0, stream>>>(W, wfrag);
    main_k<<<1024, 256, 0, stream>>>(feat, edgef, wfrag, bias, mask,
                                     (const floatx4*)adj, (floatx4*)o_adj,
                                     o_res, o_out, o_m);
}

// Round 2
// 272.614 us; speedup vs baseline: 1.0434x; 1.0434x over previous
//
#include <hip/hip_runtime.h>
#include <hip/hip_bf16.h>

typedef __attribute__((ext_vector_type(8))) short short8;
typedef __attribute__((ext_vector_type(4))) float floatx4;

#define NN     4096
#define DIN    128
#define EDIM   192
#define DMODEL 128

__device__ __forceinline__ unsigned short f2bf(float f) {
    union { float f; unsigned int i; } x; x.f = f;
    unsigned int u = x.i;
    u += 0x7FFFu + ((u >> 16) & 1u);   // RNE
    return (unsigned short)(u >> 16);
}

__device__ __forceinline__ unsigned int pk2(float lo, float hi) {
    union { __hip_bfloat162 v; unsigned int u; } cv;
    cv.v = __float22bfloat162_rn(make_float2(lo, hi));
    return cv.u;
}

__device__ __forceinline__ short8 cvt8(const float4 a, const float4 b) {
    union { short8 s; unsigned int u[4]; } r;
    r.u[0] = pk2(a.x, a.y);
    r.u[1] = pk2(a.z, a.w);
    r.u[2] = pk2(b.x, b.y);
    r.u[3] = pk2(b.z, b.w);
    return r.s;
}

// async 16B global->LDS copy; LDS dest is wave-uniform base + lane*16 (HW adds).
__device__ __forceinline__ void gl_lds16(const void* g, void* l) {
    __builtin_amdgcn_global_load_lds(
        (const __attribute__((address_space(1))) unsigned int*)g,
        (__attribute__((address_space(3))) unsigned int*)l,
        16, 0, 0);
}

// Pack W (576x128 fp32, row-major, original k = 3c+j feat / 384+e edge) into
// bf16 MFMA B-fragment order under PERMUTED k-order kt = j*128+c (feat), kt=k (edge):
// wf[((gs*8+ct)*64+lane)*8+jj] = bf16(W[korig(kt)*128 + ct*16 + (lane&15)]),
// kt = gs*32 + (lane>>4)*8 + jj.
__global__ void prep_w(const float* __restrict__ W, unsigned short* __restrict__ wf) {
    const int t = blockIdx.x * 256 + threadIdx.x;      // 288*256 == 73728 exactly
    const int jj   = t & 7;
    const int lane = (t >> 3) & 63;
    const int ct   = (t >> 9) & 7;
    const int gs   = t >> 12;
    const int kt = gs * 32 + ((lane >> 4) << 3) + jj;
    const int korig = (kt < 384) ? ((kt & 127) * 3 + (kt >> 7)) : kt;
    const int n = ct * 16 + (lane & 15);
    wf[t] = f2bf(W[korig * DMODEL + n]);
}

// Fused main kernel. 512 blocks x 4 waves; block owns 128 rows x 128 cols of
// batch b. B-fragments (W) are DMA'd into LDS once per block per stage
// (double-buffered, 8KB/stage) and shared by all 4 waves; A rows are
// prefetched one stage ahead into registers. __syncthreads' vmcnt(0) drain
// guarantees DMA + A-prefetch have landed before the next iteration reads.
__global__ __launch_bounds__(256, 2) void main_k(
    const float* __restrict__ feat,
    const float* __restrict__ edgef,
    const unsigned short* __restrict__ wfrag,
    const float* __restrict__ bias,
    const float* __restrict__ mask,
    const floatx4* __restrict__ adj4,
    floatx4* __restrict__ o_adj4,
    float* __restrict__ o_res,
    float* __restrict__ o_out,
    float* __restrict__ o_m)
{
    __shared__ __align__(16) char lbuf[2][8192];   // B-fragment double buffer
    __shared__ float m3s[128];

    const int tid  = threadIdx.x;
    const int lane = tid & 63;
    const int wv   = tid >> 6;
    const int nn   = lane & 15;
    const int quad = lane >> 4;

    const int blk = blockIdx.x;
    const int b   = blk >> 5;                 // batch 0..15
    const int i0  = (blk & 31) << 7;          // 128-row tile base
    const int p   = b & 3;

    const float* fb = feat  + (size_t)b * NN * DIN;
    const float* eb = edgef + (size_t)b * NN * EDIM;
    const int rowb = i0 + wv * 32 + nn;       // A-row base (rt adds 16)

    // ---- m3 (3-window mask max) into LDS; blocks b<4 also emit output 3 ----
    if (tid < 128) {
        const int i = i0 + tid;
        float v = mask[p * NN + i];
        if (i + 1 < NN) v = fmaxf(v, mask[p * NN + i + 1]);
        if (i + 2 < NN) v = fmaxf(v, mask[p * NN + i + 2]);
        m3s[tid] = v;
        if (b < 4) o_m[p * NN + i] = v;
    }

    // ---- stage/prefetch helpers ----
    const char* wsrc = (const char*)wfrag;

    auto stageB = [&](int s, int bi) {
        // copy 8KB stage s of W-fragments into lbuf[bi]; wave wv covers 2KB.
        const char* src = wsrc + s * 8192 + wv * 2048 + lane * 16;
        char* dst = &lbuf[bi][wv * 2048];
        gl_lds16(src, dst);
        gl_lds16(src + 1024, dst + 1024);
    };

    const float4 zf4 = make_float4(0.f, 0.f, 0.f, 0.f);

    auto loadA = [&](int s, float4& a00, float4& a01, float4& a10, float4& a11) {
        if (s < 12) {                         // feature region: j = s>>2, sl = s&3
            const int j = s >> 2, sl = s & 3;
            const int off = sl * 32 + quad * 8;
            const int r0 = rowb + j;
            a00 = zf4; a01 = zf4;
            if (r0 < NN) {
                const float* sp = fb + (size_t)r0 * DIN + off;
                a00 = *(const float4*)sp; a01 = *(const float4*)(sp + 4);
            }
            const int r1 = rowb + 16 + j;
            a10 = zf4; a11 = zf4;
            if (r1 < NN) {
                const float* sp = fb + (size_t)r1 * DIN + off;
                a10 = *(const float4*)sp; a11 = *(const float4*)(sp + 4);
            }
        } else {                              // edge region: eg = s-12; rows < NN always
            const int eg = s - 12;
            const int off = eg * 32 + quad * 8;
            const float* sp0 = eb + (size_t)rowb * EDIM + off;
            a00 = *(const float4*)sp0; a01 = *(const float4*)(sp0 + 4);
            const float* sp1 = eb + (size_t)(rowb + 16) * EDIM + off;
            a10 = *(const float4*)sp1; a11 = *(const float4*)(sp1 + 4);
        }
    };

    floatx4 acc[2][8];
    #pragma unroll
    for (int rt = 0; rt < 2; ++rt)
        #pragma unroll
        for (int ct = 0; ct < 8; ++ct)
            acc[rt][ct] = (floatx4){0.f, 0.f, 0.f, 0.f};

    // ---- prologue: stage 0 B via DMA, A(0) into regs ----
    float4 a00, a01, a10, a11, n00, n01, n10, n11;
    stageB(0, 0);
    loadA(0, a00, a01, a10, a11);
    __syncthreads();                          // drains vmcnt -> buf0 + A(0) ready

    // ---- 18-stage main loop (12 feature + 6 edge) ----
    #pragma unroll
    for (int s = 0; s < 18; ++s) {
        const int cur = s & 1;
        if (s < 17) {
            stageB(s + 1, cur ^ 1);           // DMA next stage into other buffer
            loadA(s + 1, n00, n01, n10, n11); // prefetch next A into regs
        }
        const short8* bl = (const short8*)(&lbuf[cur][0]);
        const short8 af0 = cvt8(a00, a01);
        const short8 af1 = cvt8(a10, a11);
        #pragma unroll
        for (int ct = 0; ct < 8; ++ct) {
            const short8 bfr = bl[ct * 64 + lane];
            acc[0][ct] = __builtin_amdgcn_mfma_f32_16x16x32_bf16(af0, bfr, acc[0][ct], 0, 0, 0);
            acc[1][ct] = __builtin_amdgcn_mfma_f32_16x16x32_bf16(af1, bfr, acc[1][ct], 0, 0, 0);
        }
        a00 = n00; a01 = n01; a10 = n10; a11 = n11;
        __syncthreads();                      // reads of cur done; DMA+A drained
    }

    // ---- epilogue: bias + ReLU, jump (3-row feature mean), mask, fp32 stores ----
    float biasv[8];
    #pragma unroll
    for (int ct = 0; ct < 8; ++ct)
        biasv[ct] = bias[ct * 16 + nn];

    const float inv3 = 1.0f / 3.0f;

    #pragma unroll
    for (int rt = 0; rt < 2; ++rt) {
        const int rbase = wv * 32 + rt * 16 + quad * 4;   // C/D: row = quad*4 + reg
        float mv[4];
        #pragma unroll
        for (int reg = 0; reg < 4; ++reg)
            mv[reg] = m3s[rbase + reg];
        #pragma unroll
        for (int ct = 0; ct < 8; ++ct) {
            const int col = ct * 16 + nn;                 // C/D: col = lane&15
            float fv[6];
            #pragma unroll
            for (int t6 = 0; t6 < 6; ++t6) {
                const int row = i0 + rbase + t6;
                fv[t6] = (row < NN) ? fb[(size_t)row * DIN + col] : 0.f;
            }
            #pragma unroll
            for (int reg = 0; reg < 4; ++reg) {
                float o = acc[rt][ct][reg] + biasv[ct];
                o = fmaxf(o, 0.f);
                const float jmp = (fv[reg] + fv[reg + 1] + fv[reg + 2]) * inv3;
                const size_t off = ((size_t)b * NN + (i0 + rbase + reg)) * DMODEL + col;
                const float mm = mv[reg];
                __builtin_nontemporal_store(mm * o, &o_out[off]);
                __builtin_nontemporal_store(mm * (o + jmp), &o_res[off]);
            }
        }
    }

    // ---- adj passthrough slice: 512 blocks x 256 thr x 32 float4 = 4096*4096 ----
    {
        const int idx = blk * 256 + tid;                  // 131072 threads
        #pragma unroll
        for (int i = 0; i < 32; ++i) {
            const floatx4 v = __builtin_nontemporal_load(&adj4[idx + i * 131072]);
            __builtin_nontemporal_store(v, &o_adj4[idx + i * 131072]);
        }
    }
}

extern "C" void kernel_launch(void* const* d_in, const int* in_sizes, int n_in,
                              void* d_out, int out_size, void* d_ws, size_t ws_size,
                              hipStream_t stream) {
    const float* adj   = (const float*)d_in[0];
    const float* feat  = (const float*)d_in[1];
    const float* edgef = (const float*)d_in[2];
    const float* mask  = (const float*)d_in[3];
    const float* W     = (const float*)d_in[4];
    const float* bias  = (const float*)d_in[5];

    float* out   = (float*)d_out;
    float* o_adj = out;
    float* o_res = out + (size_t)16777216;              // 4096*4096
    float* o_out = o_res + (size_t)8388608;             // 16*4096*128
    float* o_m   = o_out + (size_t)8388608;             // + 16*4096*128 -> 4*4096 tail

    unsigned short* wfrag = (unsigned short*)d_ws;      // 73728 * 2 B

    prep_w<<<288, 256, 0, stream>>>(W, wfrag);
    main_k<<<512, 256, 0, stream>>>(feat, edgef, wfrag, bias, mask,
                                    (const floatx4*)adj, (floatx4*)o_adj,
                                    o_res, o_out, o_m);
}

// Round 4
// 263.961 us; speedup vs baseline: 1.0776x; 1.0328x over previous
//
#include <hip/hip_runtime.h>
#include <hip/hip_bf16.h>

typedef __attribute__((ext_vector_type(8))) short short8;
typedef __attribute__((ext_vector_type(4))) float floatx4;

#define NN     4096
#define DIN    128
#define EDIM   192
#define DMODEL 128

__device__ __forceinline__ unsigned short f2bf(float f) {
    union { float f; unsigned int i; } x; x.f = f;
    unsigned int u = x.i;
    u += 0x7FFFu + ((u >> 16) & 1u);   // RNE
    return (unsigned short)(u >> 16);
}

__device__ __forceinline__ unsigned int pk2(float lo, float hi) {
    union { __hip_bfloat162 v; unsigned int u; } cv;
    cv.v = __float22bfloat162_rn(make_float2(lo, hi));
    return cv.u;
}

__device__ __forceinline__ short8 cvt8(const float4 a, const float4 b) {
    union { short8 s; unsigned int u[4]; } r;
    r.u[0] = pk2(a.x, a.y);
    r.u[1] = pk2(a.z, a.w);
    r.u[2] = pk2(b.x, b.y);
    r.u[3] = pk2(b.z, b.w);
    return r.s;
}

// async 16B global->LDS copy; LDS dest is wave-uniform base + lane*16 (HW adds).
__device__ __forceinline__ void gl_lds16(const void* g, void* l) {
    __builtin_amdgcn_global_load_lds(
        (const __attribute__((address_space(1))) unsigned int*)g,
        (__attribute__((address_space(3))) unsigned int*)l,
        16, 0, 0);
}

// Pack W (576x128 fp32, row-major, original k = 3c+j feat / 384+e edge) into
// bf16 MFMA B-fragment order under PERMUTED k-order kt = j*128+c (feat), kt=k (edge):
// wf[((gs*8+ct)*64+lane)*8+jj] = bf16(W[korig(kt)*128 + ct*16 + (lane&15)]),
// kt = gs*32 + (lane>>4)*8 + jj.
__global__ void prep_w(const float* __restrict__ W, unsigned short* __restrict__ wf) {
    const int t = blockIdx.x * 256 + threadIdx.x;      // 288*256 == 73728 exactly
    const int jj   = t & 7;
    const int lane = (t >> 3) & 63;
    const int ct   = (t >> 9) & 7;
    const int gs   = t >> 12;
    const int kt = gs * 32 + ((lane >> 4) << 3) + jj;
    const int korig = (kt < 384) ? ((kt & 127) * 3 + (kt >> 7)) : kt;
    const int n = ct * 16 + (lane & 15);
    wf[t] = f2bf(W[korig * DMODEL + n]);
}

// Fused main kernel. 512 blocks x 4 waves; block owns 128 rows x 128 cols of
// batch b. B-fragments (W) DMA'd to LDS (double-buffered), A prefetched one
// stage ahead. The adj passthrough (64MB r + 64MB w) is INTERLEAVED into the
// 18 GEMM stages (2 float4 chunks per stage, ping-pong regs) so its streaming
// traffic fills the GEMM's memory-latency bubbles instead of running as a
// serial tail phase. The per-stage __syncthreads vmcnt(0) drain guarantees
// each pair has arrived before it is stored one stage later.
__global__ __launch_bounds__(256, 2) void main_k(
    const float* __restrict__ feat,
    const float* __restrict__ edgef,
    const unsigned short* __restrict__ wfrag,
    const float* __restrict__ bias,
    const float* __restrict__ mask,
    const floatx4* __restrict__ adj4,
    floatx4* __restrict__ o_adj4,
    float* __restrict__ o_res,
    float* __restrict__ o_out,
    float* __restrict__ o_m)
{
    __shared__ __align__(16) char lbuf[2][8192];   // B-fragment double buffer
    __shared__ float m3s[128];

    const int tid  = threadIdx.x;
    const int lane = tid & 63;
    const int wv   = tid >> 6;
    const int nn   = lane & 15;
    const int quad = lane >> 4;

    const int blk = blockIdx.x;
    const int b   = blk >> 5;                 // batch 0..15
    const int i0  = (blk & 31) << 7;          // 128-row tile base
    const int p   = b & 3;

    const float* fb = feat  + (size_t)b * NN * DIN;
    const float* eb = edgef + (size_t)b * NN * EDIM;
    const int rowb = i0 + wv * 32 + nn;       // A-row base (rt adds 16)
    const int adjbase = blk * 256 + tid;      // adj chunk c at adjbase + c*131072

    // ---- m3 (3-window mask max) into LDS; blocks b<4 also emit output 3 ----
    if (tid < 128) {
        const int i = i0 + tid;
        float v = mask[p * NN + i];
        if (i + 1 < NN) v = fmaxf(v, mask[p * NN + i + 1]);
        if (i + 2 < NN) v = fmaxf(v, mask[p * NN + i + 2]);
        m3s[tid] = v;
        if (b < 4) o_m[p * NN + i] = v;
    }

    // ---- stage/prefetch helpers ----
    const char* wsrc = (const char*)wfrag;

    auto stageB = [&](int s, int bi) {
        // copy 8KB stage s of W-fragments into lbuf[bi]; wave wv covers 2KB.
        const char* src = wsrc + s * 8192 + wv * 2048 + lane * 16;
        char* dst = &lbuf[bi][wv * 2048];
        gl_lds16(src, dst);
        gl_lds16(src + 1024, dst + 1024);
    };

    const float4 zf4 = make_float4(0.f, 0.f, 0.f, 0.f);

    auto loadA = [&](int s, float4& a00, float4& a01, float4& a10, float4& a11) {
        if (s < 12) {                         // feature region: j = s>>2, sl = s&3
            const int j = s >> 2, sl = s & 3;
            const int off = sl * 32 + quad * 8;
            const int r0 = rowb + j;
            a00 = zf4; a01 = zf4;
            if (r0 < NN) {
                const float* sp = fb + (size_t)r0 * DIN + off;
                a00 = *(const float4*)sp; a01 = *(const float4*)(sp + 4);
            }
            const int r1 = rowb + 16 + j;
            a10 = zf4; a11 = zf4;
            if (r1 < NN) {
                const float* sp = fb + (size_t)r1 * DIN + off;
                a10 = *(const float4*)sp; a11 = *(const float4*)(sp + 4);
            }
        } else {                              // edge region: eg = s-12; rows < NN always
            const int eg = s - 12;
            const int off = eg * 32 + quad * 8;
            const float* sp0 = eb + (size_t)rowb * EDIM + off;
            a00 = *(const float4*)sp0; a01 = *(const float4*)(sp0 + 4);
            const float* sp1 = eb + (size_t)(rowb + 16) * EDIM + off;
            a10 = *(const float4*)sp1; a11 = *(const float4*)(sp1 + 4);
        }
    };

    floatx4 acc[2][8];
    #pragma unroll
    for (int rt = 0; rt < 2; ++rt)
        #pragma unroll
        for (int ct = 0; ct < 8; ++ct)
            acc[rt][ct] = (floatx4){0.f, 0.f, 0.f, 0.f};

    // ---- prologue: stage 0 B via DMA, A(0) into regs, adj pair 0 in flight ----
    float4 a00, a01, a10, a11, n00, n01, n10, n11;
    floatx4 avA0, avA1, avB0, avB1;
    stageB(0, 0);
    loadA(0, a00, a01, a10, a11);
    avA0 = __builtin_nontemporal_load(&adj4[adjbase]);
    avA1 = __builtin_nontemporal_load(&adj4[adjbase + 131072]);
    __syncthreads();                          // drains vmcnt -> buf0 + A(0) + pair0 ready

    // ---- 18-stage main loop (12 feature + 6 edge), adj interleaved ----
    #pragma unroll
    for (int s = 0; s < 18; ++s) {
        const int cur = s & 1;

        // adj: store pair s (arrived, guaranteed by previous barrier's drain),
        // issue pair s+1 into the other register set.
        if (s < 16) {
            if ((s & 1) == 0) {
                __builtin_nontemporal_store(avA0, &o_adj4[adjbase + (size_t)(2 * s) * 131072]);
                __builtin_nontemporal_store(avA1, &o_adj4[adjbase + (size_t)(2 * s + 1) * 131072]);
                if (s < 15) {
                    avB0 = __builtin_nontemporal_load(&adj4[adjbase + (size_t)(2 * s + 2) * 131072]);
                    avB1 = __builtin_nontemporal_load(&adj4[adjbase + (size_t)(2 * s + 3) * 131072]);
                }
            } else {
                __builtin_nontemporal_store(avB0, &o_adj4[adjbase + (size_t)(2 * s) * 131072]);
                __builtin_nontemporal_store(avB1, &o_adj4[adjbase + (size_t)(2 * s + 1) * 131072]);
                if (s < 15) {
                    avA0 = __builtin_nontemporal_load(&adj4[adjbase + (size_t)(2 * s + 2) * 131072]);
                    avA1 = __builtin_nontemporal_load(&adj4[adjbase + (size_t)(2 * s + 3) * 131072]);
                }
            }
        }

        if (s < 17) {
            stageB(s + 1, cur ^ 1);           // DMA next B stage into other buffer
            loadA(s + 1, n00, n01, n10, n11); // prefetch next A into regs
        }

        const short8* bl = (const short8*)(&lbuf[cur][0]);
        const short8 af0 = cvt8(a00, a01);
        const short8 af1 = cvt8(a10, a11);
        #pragma unroll
        for (int ct = 0; ct < 8; ++ct) {
            const short8 bfr = bl[ct * 64 + lane];
            acc[0][ct] = __builtin_amdgcn_mfma_f32_16x16x32_bf16(af0, bfr, acc[0][ct], 0, 0, 0);
            acc[1][ct] = __builtin_amdgcn_mfma_f32_16x16x32_bf16(af1, bfr, acc[1][ct], 0, 0, 0);
        }
        a00 = n00; a01 = n01; a10 = n10; a11 = n11;
        __syncthreads();                      // reads of cur done; DMA+A+adj drained
    }

    // ---- epilogue: bias + ReLU, jump (3-row feature mean), mask, fp32 stores ----
    float biasv[8];
    #pragma unroll
    for (int ct = 0; ct < 8; ++ct)
        biasv[ct] = bias[ct * 16 + nn];

    const float inv3 = 1.0f / 3.0f;

    #pragma unroll
    for (int rt = 0; rt < 2; ++rt) {
        const int rbase = wv * 32 + rt * 16 + quad * 4;   // C/D: row = quad*4 + reg
        float mv[4];
        #pragma unroll
        for (int reg = 0; reg < 4; ++reg)
            mv[reg] = m3s[rbase + reg];
        #pragma unroll
        for (int ct = 0; ct < 8; ++ct) {
            const int col = ct * 16 + nn;                 // C/D: col = lane&15
            float fv[6];
            #pragma unroll
            for (int t6 = 0; t6 < 6; ++t6) {
                const int row = i0 + rbase + t6;
                fv[t6] = (row < NN) ? fb[(size_t)row * DIN + col] : 0.f;
            }
            #pragma unroll
            for (int reg = 0; reg < 4; ++reg) {
                float o = acc[rt][ct][reg] + biasv[ct];
                o = fmaxf(o, 0.f);
                const float jmp = (fv[reg] + fv[reg + 1] + fv[reg + 2]) * inv3;
                const size_t off = ((size_t)b * NN + (i0 + rbase + reg)) * DMODEL + col;
                const float mm = mv[reg];
                __builtin_nontemporal_store(mm * o, &o_out[off]);
                __builtin_nontemporal_store(mm * (o + jmp), &o_res[off]);
            }
        }
    }
}

extern "C" void kernel_launch(void* const* d_in, const int* in_sizes, int n_in,
                              void* d_out, int out_size, void* d_ws, size_t ws_size,
                              hipStream_t stream) {
    const float* adj   = (const float*)d_in[0];
    const float* feat  = (const float*)d_in[1];
    const float* edgef = (const float*)d_in[2];
    const float* mask  = (const float*)d_in[3];
    const float* W     = (const float*)d_in[4];
    const float* bias  = (const float*)d_in[5];

    float* out   = (float*)d_out;
    float* o_adj = out;
    float* o_res = out + (size_t)16777216;              // 4096*4096
    float* o_out = o_res + (size_t)8388608;             // 16*4096*128
    float* o_m   = o_out + (size_t)8388608;             // + 16*4096*128 -> 4*4096 tail

    unsigned short* wfrag = (unsigned short*)d_ws;      // 73728 * 2 B

    prep_w<<<288, 256, 0, stream>>>(W, wfrag);
    main_k<<<512, 256, 0, stream>>>(feat, edgef, wfrag, bias, mask,
                                    (const floatx4*)adj, (floatx4*)o_adj,
                                    o_res, o_out, o_m);
}